// Round 3
// baseline (322.600 us; speedup 1.0000x reference)
//
#include <hip/hip_runtime.h>

// x: [64, 3, 512, 512] f32, shifts: [64, 2] i32
// out[b,c,h,w] = x[b,c,(h - s0) & 511, (w - s1) & 511]
#define BATCH 64
#define CHAN  3
#define HH    512
#define WW    512
#define W4    (WW / 4)   // 128 float4 per row

// One thread per output float4. Quad-granular W-rotation is folded into the
// (still 16B-aligned) global read address; the residual 0..3-element rotation
// (wave-uniform per batch) is resolved with __shfl from lane+1 — the neighbor
// quad IS lane+1's register. Lane 63 patches its neighbor with one extra 16B
// load per wave (~1.5% extra reads, L2-resident). No LDS, no barrier.
__global__ __launch_bounds__(256) void roll_shfl_kernel(
    const float4* __restrict__ x,
    const int*    __restrict__ shifts,
    float4*       __restrict__ out)
{
    const int idx = blockIdx.x * blockDim.x + threadIdx.x;  // output quad index
    const int w4  = idx & (W4 - 1);
    const int h   = (idx >> 7) & (HH - 1);
    const int bc  = idx >> 16;            // H*W4 = 65536
    const int b   = bc / CHAN;

    const int s0 = shifts[2 * b];
    const int s1 = shifts[2 * b + 1];

    const int hs = (h - s0) & (HH - 1);         // source row
    const int d  = (-s1) & (WW - 1);            // element rotation
    const int qd = d >> 2;                      // quad-granular part
    const int rd = d & 3;                       // intra-quad part (uniform/wave)

    const int qs = (w4 + qd) & (W4 - 1);        // source quad (consecutive per lane)
    const float4* __restrict__ src = x + ((size_t)bc * HH + hs) * W4;
    const float4 A = src[qs];

    float4 o;
    if (rd == 0) {                               // wave-uniform branch
        o = A;
    } else {
        const int lane = threadIdx.x & 63;
        const int nl   = (lane + 1) & 63;
        float4 B;
        B.x = __shfl(A.x, nl);
        B.y = __shfl(A.y, nl);
        B.z = __shfl(A.z, nl);
        B.w = __shfl(A.w, nl);
        if (lane == 63)                          // cross-wave neighbor: reload
            B = src[(qs + 1) & (W4 - 1)];
        if      (rd == 1) o = make_float4(A.y, A.z, A.w, B.x);
        else if (rd == 2) o = make_float4(A.z, A.w, B.x, B.y);
        else              o = make_float4(A.w, B.x, B.y, B.z);
    }

    out[idx] = o;
}

extern "C" void kernel_launch(void* const* d_in, const int* in_sizes, int n_in,
                              void* d_out, int out_size, void* d_ws, size_t ws_size,
                              hipStream_t stream)
{
    const float4* x      = (const float4*)d_in[0];
    const int*    shifts = (const int*)d_in[1];
    float4*       out    = (float4*)d_out;

    const int total4 = BATCH * CHAN * HH * W4;   // 12,582,912 quads
    const int block  = 256;
    const int grid   = total4 / block;

    roll_shfl_kernel<<<grid, block, 0, stream>>>(x, shifts, out);
}

// Round 4
// 318.845 us; speedup vs baseline: 1.0118x; 1.0118x over previous
//
#include <hip/hip_runtime.h>

// x: [64, 3, 512, 512] f32, shifts: [64, 2] i32
// out[b,c,h,w] = x[b,c,(h - s0) & 511, (w - s1) & 511]
#define BATCH 64
#define CHAN  3
#define HH    512
#define WW    512
#define W4    (WW / 4)   // 128 quads per row

typedef float vfloat4 __attribute__((ext_vector_type(4)));
// 16-byte vector with alignment 4: gfx950 global_load_dwordx4 only needs
// dword alignment, so this lets the compiler emit ONE wide load at a
// 4B-aligned (element-rotated) address instead of 4 scalar loads.
struct __attribute__((packed, aligned(4))) f4_a4 { vfloat4 v; };

// One thread per output float4: the entire W-rotation is folded into the
// source address (element-granular, 4B-aligned). 1 load + 1 store per thread;
// no LDS, no barrier, no cross-lane. Only the <=1 lane per row whose source
// quad wraps past the row end takes the scalar-gather path.
__global__ __launch_bounds__(256) void roll_misal_kernel(
    const float* __restrict__ x,
    const int*   __restrict__ shifts,
    vfloat4*     __restrict__ out)
{
    const int idx = blockIdx.x * blockDim.x + threadIdx.x;  // output quad index
    const int w4  = idx & (W4 - 1);
    const int h   = (idx >> 7) & (HH - 1);
    const int bc  = idx >> 16;            // H*W4 = 65536
    const int b   = bc / CHAN;

    const int s0 = shifts[2 * b];
    const int s1 = shifts[2 * b + 1];

    const int hs = (h - s0) & (HH - 1);          // source row
    const int d  = (-s1) & (WW - 1);             // element rotation
    const int e  = ((w4 << 2) + d) & (WW - 1);   // source element start

    const float* __restrict__ row = x + ((size_t)bc * HH + hs) * WW;

    vfloat4 o;
    if (e <= WW - 4) {                           // no wrap within the quad
        o = ((const f4_a4*)(row + e))->v;        // single dwordx4, align 4
    } else {                                     // quad wraps the row end
        o.x = row[e];
        o.y = row[(e + 1) & (WW - 1)];
        o.z = row[(e + 2) & (WW - 1)];
        o.w = row[(e + 3) & (WW - 1)];
    }

    out[idx] = o;
}

extern "C" void kernel_launch(void* const* d_in, const int* in_sizes, int n_in,
                              void* d_out, int out_size, void* d_ws, size_t ws_size,
                              hipStream_t stream)
{
    const float* x      = (const float*)d_in[0];
    const int*   shifts = (const int*)d_in[1];
    vfloat4*     out    = (vfloat4*)d_out;

    const int total4 = BATCH * CHAN * HH * W4;   // 12,582,912 quads
    const int block  = 256;
    const int grid   = total4 / block;

    roll_misal_kernel<<<grid, block, 0, stream>>>(x, shifts, out);
}